// Round 4
// baseline (210.295 us; speedup 1.0000x reference)
//
#include <hip/hip_runtime.h>
#include <stdint.h>

#define S_LEN 2048
#define DMODEL 1024
#define NBATCH 4
#define MROWS (NBATCH * S_LEN)  // 8192

typedef __bf16 bf16x8 __attribute__((ext_vector_type(8)));
typedef float f32x4 __attribute__((ext_vector_type(4)));

__device__ __forceinline__ unsigned short f2bf(float f) {
  unsigned int x = __builtin_bit_cast(unsigned int, f);
  x += 0x7FFFu + ((x >> 16) & 1u);
  return (unsigned short)(x >> 16);
}

template <int N>
__device__ __forceinline__ void waitvm() {
  static_assert(N >= 0 && N <= 8, "vmcnt range");
  if constexpr (N == 0) asm volatile("s_waitcnt vmcnt(0)" ::: "memory");
  else if constexpr (N == 1) asm volatile("s_waitcnt vmcnt(1)" ::: "memory");
  else if constexpr (N == 2) asm volatile("s_waitcnt vmcnt(2)" ::: "memory");
  else if constexpr (N == 3) asm volatile("s_waitcnt vmcnt(3)" ::: "memory");
  else if constexpr (N == 4) asm volatile("s_waitcnt vmcnt(4)" ::: "memory");
  else if constexpr (N == 5) asm volatile("s_waitcnt vmcnt(5)" ::: "memory");
  else if constexpr (N == 6) asm volatile("s_waitcnt vmcnt(6)" ::: "memory");
  else if constexpr (N == 7) asm volatile("s_waitcnt vmcnt(7)" ::: "memory");
  else asm volatile("s_waitcnt vmcnt(8)" ::: "memory");
}
#define BARRIER() do { __builtin_amdgcn_s_barrier(); asm volatile("" ::: "memory"); } while (0)

// ---------------- convert f32 -> bf16 (vectorized) ----------------
__global__ void cvt_kernel(const float* __restrict__ src, ushort4* __restrict__ dst, int n4) {
  int i = blockIdx.x * blockDim.x + threadIdx.x;
  if (i < n4) {
    float4 v = reinterpret_cast<const float4*>(src)[i];
    ushort4 o;
    o.x = f2bf(v.x); o.y = f2bf(v.y); o.z = f2bf(v.z); o.w = f2bf(v.w);
    dst[i] = o;
  }
}

// ---------------- 8-phase GEMM: C = A * B^T ----------------
// A: [M x K] bf16 row-major (lda); Bm: [N x K] bf16 row-major (ldb).
// 512 threads = 8 waves (2M x 4N). BN=256 fixed, BM in {128,256}. BK=64.
// Per K-tile: 4 phases = {ds_read this phase's quadrant frags (HOISTED above
// the barrier -- LDS latency overlaps vmcnt/barrier/other waves' MFMA),
// stage 1 half of tile t+1, counted vmcnt, barrier, setprio+MFMA, barrier}.
// Stage order [A0,B0,A1,B1]; quadrant order [(A0,B0),(A1,B0),(A1,B1),(A0,B1)].
// New-half consumption: p0 needs A0+B0, p1 needs A1, p2 needs B1, p3 none.
// Because frag reads are hoisted, each phase's vmcnt guards the half first
// READ at the NEXT phase. Derived steady vmcnt (loads after the guarded
// half's stage): BM=256 -> 4 at p0/p1/p3, none at p2; BM=128 -> 3.
// Quadrant (mh,nh) reads EXACTLY the staged contiguous halves across waves:
//   A row = mh*(BM/2) + wm*(BM/4) + m*16 + frow
//   B row = nh*128    + wn*32     + nn*16 + frow
// LDS swizzle: 16B-slot index ^= (row&7), via pre-swizzled GLOBAL source
// (linear LDS dest, rule #21) and identically on ds_read.
// EP: 0 = bf16 out + bias[col]; 1 = f32 out * scale; 2 = f32 out
template <int BM_, int EP>
__global__ __launch_bounds__(512, 2) void gemm8(
    const unsigned short* __restrict__ A, const unsigned short* __restrict__ Bm,
    void* __restrict__ Cp, const float* __restrict__ bias,
    int lda, int ldb, int ldc, int NT, float scale,
    long zsA, long zsB, long zsC) {
  constexpr int BN_ = 256;
  constexpr int BK = 64;                 // elements (128 bytes)
  constexpr int RA = BM_ / 128;          // stage loads per A-half per wave
  constexpr int HALF_A = (BM_ / 2) * 128;  // bytes
  constexpr int HALF_B = 128 * 128;
  constexpr int ATILE = BM_ * 128;
  constexpr int BTILE = BN_ * 128;
  constexpr int MREP = BM_ / 32;         // 8 or 4
  constexpr int MQ = MREP / 2;           // A frags per quadrant (4 or 2)
  constexpr int VM = (BM_ == 256) ? 4 : 3;  // steady/prologue counted vmcnt

  __shared__ alignas(16) char lds[(ATILE + BTILE) * 2];

  const int tid = threadIdx.x;
  const int l = tid & 63;
  const int w = tid >> 6;   // 0..7
  const int wm = w >> 2;    // 0..1
  const int wn = w & 3;     // 0..3

  // bijective XCD-chunked swizzle (nwg % 8 == 0 for all our grids)
  const int gx = gridDim.x;
  const int nwg = gridDim.x * gridDim.y;
  int n = blockIdx.y * gx + blockIdx.x;
  int n2 = (n & 7) * (nwg >> 3) + (n >> 3);
  const int tileM = (n2 / gx) * BM_;
  const int tileN = (n2 % gx) * BN_;

  const int z = blockIdx.z;
  const unsigned short* Ab = A + (size_t)z * zsA;
  const unsigned short* Bb = Bm + (size_t)z * zsB;

  // staging: per-lane pre-swizzled global col; linear LDS dest (wave-uniform base)
  const int srow = l >> 3;                       // 0..7 within 8-row wave chunk
  const int scol = (((l & 7) ^ srow) * 16);      // swizzled byte col within 128B row

  auto stageA = [&](int buf, int t, int h) {
#pragma unroll
    for (int r = 0; r < RA; ++r) {
      int row = h * (BM_ / 2) + r * 64 + w * 8 + srow;
      const char* g = (const char*)(Ab + (size_t)(tileM + row) * lda + t * BK) + scol;
      char* d = lds + buf * (ATILE + BTILE) + h * HALF_A + r * 8192 + w * 1024;
      __builtin_amdgcn_global_load_lds(
          (const __attribute__((address_space(1))) void*)g,
          (__attribute__((address_space(3))) void*)d, 16, 0, 0);
    }
  };
  auto stageB = [&](int buf, int t, int h) {
#pragma unroll
    for (int r = 0; r < 2; ++r) {
      int row = h * 128 + r * 64 + w * 8 + srow;
      const char* g = (const char*)(Bb + (size_t)(tileN + row) * ldb + t * BK) + scol;
      char* d = lds + buf * (ATILE + BTILE) + ATILE + h * HALF_B + r * 8192 + w * 1024;
      __builtin_amdgcn_global_load_lds(
          (const __attribute__((address_space(1))) void*)g,
          (__attribute__((address_space(3))) void*)d, 16, 0, 0);
    }
  };

  f32x4 acc[MREP][4];
#pragma unroll
  for (int m = 0; m < MREP; ++m)
#pragma unroll
    for (int nn = 0; nn < 4; ++nn) acc[m][nn] = f32x4{0.f, 0.f, 0.f, 0.f};

  // fragment ds_read (same XOR swizzle as staging)
  const int frow = l & 15;
  auto rdA = [&](int buf, int mh, int m, int kk) -> bf16x8 {
    int row = mh * (BM_ / 2) + wm * (BM_ / 4) + m * 16 + frow;
    int col = (kk * 64 + ((l >> 4) * 16)) ^ ((row & 7) << 4);
    return *reinterpret_cast<const bf16x8*>(lds + buf * (ATILE + BTILE) + row * 128 + col);
  };
  auto rdB = [&](int buf, int nh, int nn, int kk) -> bf16x8 {
    int row = nh * 128 + wn * 32 + nn * 16 + frow;
    int col = (kk * 64 + ((l >> 4) * 16)) ^ ((row & 7) << 4);
    return *reinterpret_cast<const bf16x8*>(lds + buf * (ATILE + BTILE) + ATILE + row * 128 + col);
  };

  bf16x8 av[MQ][2], bv[2][2];
  auto readfr = [&](int buf, int mh, int nh) {
#pragma unroll
    for (int m = 0; m < MQ; ++m)
#pragma unroll
      for (int kk = 0; kk < 2; ++kk) av[m][kk] = rdA(buf, mh, m, kk);
#pragma unroll
    for (int nn = 0; nn < 2; ++nn)
#pragma unroll
      for (int kk = 0; kk < 2; ++kk) bv[nn][kk] = rdB(buf, nh, nn, kk);
  };
  auto domfma = [&](int mh, int nh) {
    __builtin_amdgcn_s_setprio(1);
#pragma unroll
    for (int m = 0; m < MQ; ++m)
#pragma unroll
      for (int nn = 0; nn < 2; ++nn)
#pragma unroll
        for (int kk = 0; kk < 2; ++kk)
          acc[mh * MQ + m][nh * 2 + nn] = __builtin_amdgcn_mfma_f32_16x16x32_bf16(
              av[m][kk], bv[nn][kk], acc[mh * MQ + m][nh * 2 + nn], 0, 0, 0);
    __builtin_amdgcn_s_setprio(0);
  };

  // prologue: stage tile 0 fully; guarantee A0,B0 resident before p0's reads
  stageA(0, 0, 0);
  stageB(0, 0, 0);
  stageA(0, 0, 1);
  stageB(0, 0, 1);
  waitvm<VM>();   // outstanding <= A1,B1
  BARRIER();

  for (int t = 0; t < NT - 1; ++t) {
    const int buf = t & 1, nb = buf ^ 1;
    // p0: quadrant (A0,B0); stage A0(t+1); vm guards A1(t) for p1's reads
    readfr(buf, 0, 0); stageA(nb, t + 1, 0); waitvm<VM>(); BARRIER(); domfma(0, 0); BARRIER();
    // p1: quadrant (A1,B0); stage B0(t+1); vm guards B1(t) for p2's reads
    readfr(buf, 1, 0); stageB(nb, t + 1, 0); waitvm<VM>(); BARRIER(); domfma(1, 0); BARRIER();
    // p2: quadrant (A1,B1); stage A1(t+1); p3 reads nothing new -> no vmcnt
    readfr(buf, 1, 1); stageA(nb, t + 1, 1); BARRIER(); domfma(1, 1); BARRIER();
    // p3: quadrant (A0,B1); stage B1(t+1); vm guards A0(t+1),B0(t+1)
    readfr(buf, 0, 1); stageB(nb, t + 1, 1); waitvm<VM>(); BARRIER(); domfma(0, 1); BARRIER();
  }
  {  // peeled last tile: no staging; drain counted waits
    const int buf = (NT - 1) & 1;
    readfr(buf, 0, 0); waitvm<2>(); BARRIER(); domfma(0, 0); BARRIER();
    readfr(buf, 1, 0); waitvm<0>(); BARRIER(); domfma(1, 0); BARRIER();
    readfr(buf, 1, 1);              BARRIER(); domfma(1, 1); BARRIER();
    readfr(buf, 0, 1);              BARRIER(); domfma(0, 1);
  }

  // epilogue: C/D layout (m89): col = lane&15, row = (lane>>4)*4 + j
  const int lr = (l >> 4) * 4;
  const int lc = l & 15;
#pragma unroll
  for (int mh = 0; mh < 2; ++mh) {
#pragma unroll
    for (int m = 0; m < MQ; ++m) {
#pragma unroll
      for (int nh = 0; nh < 2; ++nh) {
#pragma unroll
        for (int nn = 0; nn < 2; ++nn) {
          int gr = tileM + mh * (BM_ / 2) + wm * (BM_ / 4) + m * 16 + lr;
          int gc = tileN + nh * 128 + wn * 32 + nn * 16 + lc;
          f32x4 v = acc[mh * MQ + m][nh * 2 + nn];
          if constexpr (EP == 0) {
            float bb = bias[gc];
            unsigned short* C = (unsigned short*)Cp + (size_t)z * zsC;
#pragma unroll
            for (int j = 0; j < 4; ++j) C[(size_t)(gr + j) * ldc + gc] = f2bf(v[j] + bb);
          } else {
            float* C = (float*)Cp + (size_t)z * zsC;
#pragma unroll
            for (int j = 0; j < 4; ++j)
              C[(size_t)(gr + j) * ldc + gc] = (EP == 1) ? v[j] * scale : v[j];
          }
        }
      }
    }
  }
}

// ---------------- transpose bf16 V cols of QKV [S x 3072] -> Vt [D x S] per batch ----------------
__global__ void transpose_kernel(const unsigned short* __restrict__ src,
                                 unsigned short* __restrict__ dst) {
  __shared__ unsigned short tile[32][33];
  int b = blockIdx.z;
  int s0 = blockIdx.x * 32;
  int d0 = blockIdx.y * 32;
  int t = threadIdx.x;
  int r = t >> 3;
  int c4 = (t & 7) * 4;
  const unsigned short* sp = src + ((size_t)b * S_LEN + s0 + r) * 3072 + 2048 + d0 + c4;
  ushort4 v = *reinterpret_cast<const ushort4*>(sp);
  tile[r][c4 + 0] = v.x; tile[r][c4 + 1] = v.y; tile[r][c4 + 2] = v.z; tile[r][c4 + 3] = v.w;
  __syncthreads();
  unsigned short* dp = dst + ((size_t)b * DMODEL + d0 + r) * S_LEN + s0 + c4;
  ushort4 o;
  o.x = tile[c4 + 0][r]; o.y = tile[c4 + 1][r]; o.z = tile[c4 + 2][r]; o.w = tile[c4 + 3][r];
  *reinterpret_cast<ushort4*>(dp) = o;
}

// ---------------- row softmax: fp32 [8192 x 2048] -> bf16 P ----------------
__global__ __launch_bounds__(256) void softmax_kernel(const float* __restrict__ Sb,
                                                      unsigned short* __restrict__ P) {
  const size_t row = blockIdx.x;
  const float* sp = Sb + row * S_LEN;
  const int t = threadIdx.x;
  const int wid = t >> 6, lane = t & 63;
  float4 v0 = reinterpret_cast<const float4*>(sp)[t * 2];
  float4 v1 = reinterpret_cast<const float4*>(sp)[t * 2 + 1];
  float s[8] = {v0.x, v0.y, v0.z, v0.w, v1.x, v1.y, v1.z, v1.w};
  float mx = s[0];
#pragma unroll
  for (int i = 1; i < 8; ++i) mx = fmaxf(mx, s[i]);
#pragma unroll
  for (int o = 32; o > 0; o >>= 1) mx = fmaxf(mx, __shfl_xor(mx, o));
  __shared__ float redm[4];
  __shared__ float reds[4];
  if (lane == 0) redm[wid] = mx;
  __syncthreads();
  mx = fmaxf(fmaxf(redm[0], redm[1]), fmaxf(redm[2], redm[3]));
  float e[8];
  float sum = 0.f;
#pragma unroll
  for (int i = 0; i < 8; ++i) { e[i] = __expf(s[i] - mx); sum += e[i]; }
#pragma unroll
  for (int o = 32; o > 0; o >>= 1) sum += __shfl_xor(sum, o);
  if (lane == 0) reds[wid] = sum;
  __syncthreads();
  sum = reds[0] + reds[1] + reds[2] + reds[3];
  float inv = 1.0f / sum;
  ushort4 o0, o1;
  o0.x = f2bf(e[0] * inv); o0.y = f2bf(e[1] * inv); o0.z = f2bf(e[2] * inv); o0.w = f2bf(e[3] * inv);
  o1.x = f2bf(e[4] * inv); o1.y = f2bf(e[5] * inv); o1.z = f2bf(e[6] * inv); o1.w = f2bf(e[7] * inv);
  ushort4* dp = reinterpret_cast<ushort4*>(P + row * S_LEN);
  dp[t * 2] = o0;
  dp[t * 2 + 1] = o1;
}

extern "C" void kernel_launch(void* const* d_in, const int* in_sizes, int n_in,
                              void* d_out, int out_size, void* d_ws, size_t ws_size,
                              hipStream_t stream) {
  (void)in_sizes; (void)n_in; (void)out_size;
  const float* x = (const float*)d_in[0];
  const float* Wq = (const float*)d_in[1];
  const float* bq = (const float*)d_in[2];
  const float* Wk = (const float*)d_in[3];
  const float* bk = (const float*)d_in[4];
  const float* Wv = (const float*)d_in[5];
  const float* bv = (const float*)d_in[6];
  float* out = (float*)d_out;

  // workspace layout (bytes), total 140,509,184:
  //   xb    bf16 [8192][1024]  @ 0        (16 MB)  -- reused as Vt after QKV GEMM
  //   Wqkvb bf16 [3072][1024]  @ 16 MB    (6 MB)
  //   QKVb  bf16 [8192][3072]  @ 22 MB    (48 MB)  -- reused as P after scores GEMM
  //   Sb    f32  [4][2048][2048] @ 70 MB  (64 MB)  -- bqkv f32[3072] aliases its head
  if (ws_size < 140509184ull) return;
  char* ws = (char*)d_ws;
  unsigned short* xb    = (unsigned short*)(ws);
  unsigned short* Wqkvb = (unsigned short*)(ws + 16777216);
  unsigned short* QKVb  = (unsigned short*)(ws + 23068672);
  float*          Sb    = (float*)(ws + 73400320);
  float*          bqkv  = (float*)(ws + 73400320);  // alias: dead before Sb written
  unsigned short* Vt    = xb;                        // alias: xb dead after QKV GEMM
  unsigned short* P     = QKVb;                      // alias: QKVb dead after scores GEMM

  // 1) converts to bf16 (+ fused weight concat [Wq;Wk;Wv])
  cvt_kernel<<<dim3(MROWS * DMODEL / 4 / 256), 256, 0, stream>>>(x, (ushort4*)xb, MROWS * DMODEL / 4);
  cvt_kernel<<<dim3(1024), 256, 0, stream>>>(Wq, (ushort4*)Wqkvb, DMODEL * DMODEL / 4);
  cvt_kernel<<<dim3(1024), 256, 0, stream>>>(Wk, (ushort4*)(Wqkvb + 1048576), DMODEL * DMODEL / 4);
  cvt_kernel<<<dim3(1024), 256, 0, stream>>>(Wv, (ushort4*)(Wqkvb + 2097152), DMODEL * DMODEL / 4);
  hipMemcpyAsync(bqkv, bq, 4096, hipMemcpyDeviceToDevice, stream);
  hipMemcpyAsync(bqkv + 1024, bk, 4096, hipMemcpyDeviceToDevice, stream);
  hipMemcpyAsync(bqkv + 2048, bv, 4096, hipMemcpyDeviceToDevice, stream);

  // 2) fused QKV projection: [8192x3072] = x * Wqkv^T + bqkv (M=8192,N=3072,K=1024)
  gemm8<256, 0><<<dim3(12, 32, 1), 512, 0, stream>>>(
      xb, Wqkvb, QKVb, bqkv, 1024, 1024, 3072, 16, 1.f, 0, 0, 0);

  // 3) transpose V cols -> Vt [4][1024][2048]
  transpose_kernel<<<dim3(S_LEN / 32, DMODEL / 32, NBATCH), 256, 0, stream>>>(QKVb, Vt);

  // 4) scores: Sb = Q * K^T * 0.125 (per batch M=N=2048, K=1024; Q/K strided in QKVb)
  gemm8<256, 1><<<dim3(8, 8, 4), 512, 0, stream>>>(
      QKVb, QKVb + 1024, Sb, nullptr, 3072, 3072, 2048, 16, 0.125f,
      (long)S_LEN * 3072, (long)S_LEN * 3072, (long)S_LEN * S_LEN);

  // 5) row softmax -> bf16 P
  softmax_kernel<<<dim3(MROWS), 256, 0, stream>>>(Sb, P);

  // 6) out = P * Vt^T (per batch M=2048, N=1024, K=2048)
  gemm8<128, 2><<<dim3(4, 16, 4), 512, 0, stream>>>(
      P, Vt, out, nullptr, 2048, 2048, 1024, 32, 1.f,
      (long)S_LEN * S_LEN, (long)DMODEL * S_LEN, (long)S_LEN * DMODEL);
}

// Round 5
// 184.118 us; speedup vs baseline: 1.1422x; 1.1422x over previous
//
#include <hip/hip_runtime.h>
#include <stdint.h>

#define S_LEN 2048
#define DMODEL 1024
#define NBATCH 4
#define MROWS (NBATCH * S_LEN)  // 8192

typedef __bf16 bf16x8 __attribute__((ext_vector_type(8)));
typedef float f32x4 __attribute__((ext_vector_type(4)));

__device__ __forceinline__ unsigned short f2bf(float f) {
  unsigned int x = __builtin_bit_cast(unsigned int, f);
  x += 0x7FFFu + ((x >> 16) & 1u);
  return (unsigned short)(x >> 16);
}

template <int N>
__device__ __forceinline__ void waitvm() {
  static_assert(N >= 0 && N <= 8, "vmcnt range");
  if constexpr (N == 0) asm volatile("s_waitcnt vmcnt(0)" ::: "memory");
  else if constexpr (N == 1) asm volatile("s_waitcnt vmcnt(1)" ::: "memory");
  else if constexpr (N == 2) asm volatile("s_waitcnt vmcnt(2)" ::: "memory");
  else if constexpr (N == 3) asm volatile("s_waitcnt vmcnt(3)" ::: "memory");
  else if constexpr (N == 4) asm volatile("s_waitcnt vmcnt(4)" ::: "memory");
  else if constexpr (N == 5) asm volatile("s_waitcnt vmcnt(5)" ::: "memory");
  else if constexpr (N == 6) asm volatile("s_waitcnt vmcnt(6)" ::: "memory");
  else if constexpr (N == 7) asm volatile("s_waitcnt vmcnt(7)" ::: "memory");
  else asm volatile("s_waitcnt vmcnt(8)" ::: "memory");
}
#define BARRIER() do { __builtin_amdgcn_s_barrier(); asm volatile("" ::: "memory"); } while (0)

// ---------------- convert f32 -> bf16 (vectorized) ----------------
__global__ void cvt_kernel(const float* __restrict__ src, ushort4* __restrict__ dst, int n4) {
  int i = blockIdx.x * blockDim.x + threadIdx.x;
  if (i < n4) {
    float4 v = reinterpret_cast<const float4*>(src)[i];
    ushort4 o;
    o.x = f2bf(v.x); o.y = f2bf(v.y); o.z = f2bf(v.z); o.w = f2bf(v.w);
    dst[i] = o;
  }
}

// ---------------- 8-phase GEMM: C = A * B^T ----------------
// A: [M x K] bf16 row-major (lda); Bm: [N x K] bf16 row-major (ldb).
// 512 threads = 8 waves (2M x 4N). BN=256 fixed, BM in {128,256}. BK=64.
// ROUND-5 RESTRUCTURE (fixes LDS-read-bound): each fragment is read from LDS
// ONCE per K-tile and kept in registers across quadrants.
//   quadrant order: p0=(A0,B0) p1=(A0,B1) p2=(A1,B1) p3=(A1,B0)
//   av       = current A-half frags (filled at p0 and p2)
//   bvA/bvB  = B-half-0 / B-half-1 frags (filled at p0 / p1, reused p3 / p2)
// Reads/tile/wave: 24 (was 48). ONE barrier per phase (4/tile, was 8):
// phase = {readfr, stage 1 half of t+1, counted vmcnt, barrier, setprio+MFMA}.
// Reads at phase p are guarded by phase p-1's vmcnt+barrier.
// Stage slots (tile t stages t+1): p0->A0, p1->B0, p2->B1, p3->A1
// (matches t+1 consumption: p0 needs A0+B0, p1 needs B1, p2 needs A1).
// Derived vmcnt (loads in flight after this phase's stage, allowing all
// younger than the guarded half): BM=256: 4,4,-,4 (prologue 4; drain 2,0);
// BM=128: 2,3,-,3 (prologue 3; drain 1,0).
// Quadrant (mh,nh) reads EXACTLY the staged contiguous halves across waves:
//   A row = mh*(BM/2) + wm*(BM/4) + m*16 + frow
//   B row = nh*128    + wn*32     + nn*16 + frow
// LDS swizzle: 16B-slot index ^= (row&7), via pre-swizzled GLOBAL source
// (linear LDS dest, rule #21) and identically on ds_read.
// EP: 0 = bf16 out + bias[col]; 1 = f32 out * scale; 2 = f32 out
template <int BM_, int EP>
__global__ __launch_bounds__(512, 2) void gemm8(
    const unsigned short* __restrict__ A, const unsigned short* __restrict__ Bm,
    void* __restrict__ Cp, const float* __restrict__ bias,
    int lda, int ldb, int ldc, int NT, float scale,
    long zsA, long zsB, long zsC) {
  constexpr int BN_ = 256;
  constexpr int BK = 64;                 // elements (128 bytes)
  constexpr int RA = BM_ / 128;          // stage loads per A-half per wave
  constexpr int HALF_A = (BM_ / 2) * 128;  // bytes
  constexpr int HALF_B = 128 * 128;
  constexpr int ATILE = BM_ * 128;
  constexpr int BTILE = BN_ * 128;
  constexpr int MREP = BM_ / 32;         // 8 or 4
  constexpr int MQ = MREP / 2;           // A frags per half (4 or 2)
  constexpr int VMp = (BM_ == 256) ? 4 : 3;
  constexpr int VM0 = (BM_ == 256) ? 4 : 2;
  constexpr int VM1 = (BM_ == 256) ? 4 : 3;
  constexpr int VM3 = (BM_ == 256) ? 4 : 3;
  constexpr int VD0 = (BM_ == 256) ? 2 : 1;

  __shared__ alignas(16) char lds[(ATILE + BTILE) * 2];

  const int tid = threadIdx.x;
  const int l = tid & 63;
  const int w = tid >> 6;   // 0..7
  const int wm = w >> 2;    // 0..1
  const int wn = w & 3;     // 0..3

  // bijective XCD-chunked swizzle (nwg % 8 == 0 for all our grids)
  const int gx = gridDim.x;
  const int nwg = gridDim.x * gridDim.y;
  int n = blockIdx.y * gx + blockIdx.x;
  int n2 = (n & 7) * (nwg >> 3) + (n >> 3);
  const int tileM = (n2 / gx) * BM_;
  const int tileN = (n2 % gx) * BN_;

  const int z = blockIdx.z;
  const unsigned short* Ab = A + (size_t)z * zsA;
  const unsigned short* Bb = Bm + (size_t)z * zsB;

  // staging: per-lane pre-swizzled global col; linear LDS dest (wave-uniform base)
  const int srow = l >> 3;                       // 0..7 within 8-row wave chunk
  const int scol = (((l & 7) ^ srow) * 16);      // swizzled byte col within 128B row

  auto stageA = [&](int buf, int t, int h) {
#pragma unroll
    for (int r = 0; r < RA; ++r) {
      int row = h * (BM_ / 2) + r * 64 + w * 8 + srow;
      const char* g = (const char*)(Ab + (size_t)(tileM + row) * lda + t * BK) + scol;
      char* d = lds + buf * (ATILE + BTILE) + h * HALF_A + r * 8192 + w * 1024;
      __builtin_amdgcn_global_load_lds(
          (const __attribute__((address_space(1))) void*)g,
          (__attribute__((address_space(3))) void*)d, 16, 0, 0);
    }
  };
  auto stageB = [&](int buf, int t, int h) {
#pragma unroll
    for (int r = 0; r < 2; ++r) {
      int row = h * 128 + r * 64 + w * 8 + srow;
      const char* g = (const char*)(Bb + (size_t)(tileN + row) * ldb + t * BK) + scol;
      char* d = lds + buf * (ATILE + BTILE) + ATILE + h * HALF_B + r * 8192 + w * 1024;
      __builtin_amdgcn_global_load_lds(
          (const __attribute__((address_space(1))) void*)g,
          (__attribute__((address_space(3))) void*)d, 16, 0, 0);
    }
  };

  f32x4 acc[MREP][4];
#pragma unroll
  for (int m = 0; m < MREP; ++m)
#pragma unroll
    for (int nn = 0; nn < 4; ++nn) acc[m][nn] = f32x4{0.f, 0.f, 0.f, 0.f};

  // fragment ds_read (same XOR swizzle as staging)
  const int frow = l & 15;
  auto rdA = [&](int buf, int mh, int m, int kk) -> bf16x8 {
    int row = mh * (BM_ / 2) + wm * (BM_ / 4) + m * 16 + frow;
    int col = (kk * 64 + ((l >> 4) * 16)) ^ ((row & 7) << 4);
    return *reinterpret_cast<const bf16x8*>(lds + buf * (ATILE + BTILE) + row * 128 + col);
  };
  auto rdB = [&](int buf, int nh, int nn, int kk) -> bf16x8 {
    int row = nh * 128 + wn * 32 + nn * 16 + frow;
    int col = (kk * 64 + ((l >> 4) * 16)) ^ ((row & 7) << 4);
    return *reinterpret_cast<const bf16x8*>(lds + buf * (ATILE + BTILE) + ATILE + row * 128 + col);
  };

  bf16x8 av[MQ][2];        // current A-half
  bf16x8 bvA[2][2];        // B-half 0
  bf16x8 bvB[2][2];        // B-half 1
  auto readA = [&](int buf, int mh) {
#pragma unroll
    for (int m = 0; m < MQ; ++m)
#pragma unroll
      for (int kk = 0; kk < 2; ++kk) av[m][kk] = rdA(buf, mh, m, kk);
  };
  auto readB = [&](int buf, int nh, bf16x8 (&bv)[2][2]) {
#pragma unroll
    for (int nn = 0; nn < 2; ++nn)
#pragma unroll
      for (int kk = 0; kk < 2; ++kk) bv[nn][kk] = rdB(buf, nh, nn, kk);
  };
  auto domfma = [&](int mh, int nh, bf16x8 (&bv)[2][2]) {
    __builtin_amdgcn_s_setprio(1);
#pragma unroll
    for (int m = 0; m < MQ; ++m)
#pragma unroll
      for (int nn = 0; nn < 2; ++nn)
#pragma unroll
        for (int kk = 0; kk < 2; ++kk)
          acc[mh * MQ + m][nh * 2 + nn] = __builtin_amdgcn_mfma_f32_16x16x32_bf16(
              av[m][kk], bv[nn][kk], acc[mh * MQ + m][nh * 2 + nn], 0, 0, 0);
    __builtin_amdgcn_s_setprio(0);
  };

  // prologue: stage tile 0 in consumption order; guarantee A0,B0 before p0 reads
  stageA(0, 0, 0);
  stageB(0, 0, 0);
  stageB(0, 0, 1);
  stageA(0, 0, 1);
  waitvm<VMp>();   // A0,B0 resident; B1,A1 may be in flight
  BARRIER();

  for (int t = 0; t < NT - 1; ++t) {
    const int buf = t & 1, nb = buf ^ 1;
    // p0: (A0,B0); stage A0(t+1); guard B1(t) for p1
    readA(buf, 0); readB(buf, 0, bvA);
    stageA(nb, t + 1, 0); waitvm<VM0>(); BARRIER(); domfma(0, 0, bvA);
    // p1: (A0,B1); stage B0(t+1); guard A1(t) for p2
    readB(buf, 1, bvB);
    stageB(nb, t + 1, 0); waitvm<VM1>(); BARRIER(); domfma(0, 1, bvB);
    // p2: (A1,B1); stage B1(t+1); p3 reads nothing -> no vmcnt
    readA(buf, 1);
    stageB(nb, t + 1, 1); BARRIER(); domfma(1, 1, bvB);
    // p3: (A1,B0); stage A1(t+1); guard A0(t+1),B0(t+1) for t+1.p0
    stageA(nb, t + 1, 1); waitvm<VM3>(); BARRIER(); domfma(1, 0, bvA);
  }
  {  // peeled last tile: no staging; drain counted waits
    const int buf = (NT - 1) & 1;
    readA(buf, 0); readB(buf, 0, bvA); waitvm<VD0>(); BARRIER(); domfma(0, 0, bvA);
    readB(buf, 1, bvB);                waitvm<0>();   BARRIER(); domfma(0, 1, bvB);
    readA(buf, 1);                                               domfma(1, 1, bvB);
                                                                 domfma(1, 0, bvA);
  }

  // epilogue: C/D layout (m89): col = lane&15, row = (lane>>4)*4 + j
  const int lr = (l >> 4) * 4;
  const int lc = l & 15;
#pragma unroll
  for (int mh = 0; mh < 2; ++mh) {
#pragma unroll
    for (int m = 0; m < MQ; ++m) {
#pragma unroll
      for (int nh = 0; nh < 2; ++nh) {
#pragma unroll
        for (int nn = 0; nn < 2; ++nn) {
          int gr = tileM + mh * (BM_ / 2) + wm * (BM_ / 4) + m * 16 + lr;
          int gc = tileN + nh * 128 + wn * 32 + nn * 16 + lc;
          f32x4 v = acc[mh * MQ + m][nh * 2 + nn];
          if constexpr (EP == 0) {
            float bb = bias[gc];
            unsigned short* C = (unsigned short*)Cp + (size_t)z * zsC;
#pragma unroll
            for (int j = 0; j < 4; ++j) C[(size_t)(gr + j) * ldc + gc] = f2bf(v[j] + bb);
          } else {
            float* C = (float*)Cp + (size_t)z * zsC;
#pragma unroll
            for (int j = 0; j < 4; ++j)
              C[(size_t)(gr + j) * ldc + gc] = (EP == 1) ? v[j] * scale : v[j];
          }
        }
      }
    }
  }
}

// ---------------- transpose bf16 V cols of QKV [S x 3072] -> Vt [D x S] per batch ----------------
__global__ void transpose_kernel(const unsigned short* __restrict__ src,
                                 unsigned short* __restrict__ dst) {
  __shared__ unsigned short tile[32][33];
  int b = blockIdx.z;
  int s0 = blockIdx.x * 32;
  int d0 = blockIdx.y * 32;
  int t = threadIdx.x;
  int r = t >> 3;
  int c4 = (t & 7) * 4;
  const unsigned short* sp = src + ((size_t)b * S_LEN + s0 + r) * 3072 + 2048 + d0 + c4;
  ushort4 v = *reinterpret_cast<const ushort4*>(sp);
  tile[r][c4 + 0] = v.x; tile[r][c4 + 1] = v.y; tile[r][c4 + 2] = v.z; tile[r][c4 + 3] = v.w;
  __syncthreads();
  unsigned short* dp = dst + ((size_t)b * DMODEL + d0 + r) * S_LEN + s0 + c4;
  ushort4 o;
  o.x = tile[c4 + 0][r]; o.y = tile[c4 + 1][r]; o.z = tile[c4 + 2][r]; o.w = tile[c4 + 3][r];
  *reinterpret_cast<ushort4*>(dp) = o;
}

// ---------------- row softmax: fp32 [8192 x 2048] -> bf16 P ----------------
__global__ __launch_bounds__(256) void softmax_kernel(const float* __restrict__ Sb,
                                                      unsigned short* __restrict__ P) {
  const size_t row = blockIdx.x;
  const float* sp = Sb + row * S_LEN;
  const int t = threadIdx.x;
  const int wid = t >> 6, lane = t & 63;
  float4 v0 = reinterpret_cast<const float4*>(sp)[t * 2];
  float4 v1 = reinterpret_cast<const float4*>(sp)[t * 2 + 1];
  float s[8] = {v0.x, v0.y, v0.z, v0.w, v1.x, v1.y, v1.z, v1.w};
  float mx = s[0];
#pragma unroll
  for (int i = 1; i < 8; ++i) mx = fmaxf(mx, s[i]);
#pragma unroll
  for (int o = 32; o > 0; o >>= 1) mx = fmaxf(mx, __shfl_xor(mx, o));
  __shared__ float redm[4];
  __shared__ float reds[4];
  if (lane == 0) redm[wid] = mx;
  __syncthreads();
  mx = fmaxf(fmaxf(redm[0], redm[1]), fmaxf(redm[2], redm[3]));
  float e[8];
  float sum = 0.f;
#pragma unroll
  for (int i = 0; i < 8; ++i) { e[i] = __expf(s[i] - mx); sum += e[i]; }
#pragma unroll
  for (int o = 32; o > 0; o >>= 1) sum += __shfl_xor(sum, o);
  if (lane == 0) reds[wid] = sum;
  __syncthreads();
  sum = reds[0] + reds[1] + reds[2] + reds[3];
  float inv = 1.0f / sum;
  ushort4 o0, o1;
  o0.x = f2bf(e[0] * inv); o0.y = f2bf(e[1] * inv); o0.z = f2bf(e[2] * inv); o0.w = f2bf(e[3] * inv);
  o1.x = f2bf(e[4] * inv); o1.y = f2bf(e[5] * inv); o1.z = f2bf(e[6] * inv); o1.w = f2bf(e[7] * inv);
  ushort4* dp = reinterpret_cast<ushort4*>(P + row * S_LEN);
  dp[t * 2] = o0;
  dp[t * 2 + 1] = o1;
}

extern "C" void kernel_launch(void* const* d_in, const int* in_sizes, int n_in,
                              void* d_out, int out_size, void* d_ws, size_t ws_size,
                              hipStream_t stream) {
  (void)in_sizes; (void)n_in; (void)out_size;
  const float* x = (const float*)d_in[0];
  const float* Wq = (const float*)d_in[1];
  const float* bq = (const float*)d_in[2];
  const float* Wk = (const float*)d_in[3];
  const float* bk = (const float*)d_in[4];
  const float* Wv = (const float*)d_in[5];
  const float* bv = (const float*)d_in[6];
  float* out = (float*)d_out;

  // workspace layout (bytes), total 140,509,184:
  //   xb    bf16 [8192][1024]  @ 0        (16 MB)  -- reused as Vt after QKV GEMM
  //   Wqkvb bf16 [3072][1024]  @ 16 MB    (6 MB)
  //   QKVb  bf16 [8192][3072]  @ 22 MB    (48 MB)  -- reused as P after scores GEMM
  //   Sb    f32  [4][2048][2048] @ 70 MB  (64 MB)  -- bqkv f32[3072] aliases its head
  if (ws_size < 140509184ull) return;
  char* ws = (char*)d_ws;
  unsigned short* xb    = (unsigned short*)(ws);
  unsigned short* Wqkvb = (unsigned short*)(ws + 16777216);
  unsigned short* QKVb  = (unsigned short*)(ws + 23068672);
  float*          Sb    = (float*)(ws + 73400320);
  float*          bqkv  = (float*)(ws + 73400320);  // alias: dead before Sb written
  unsigned short* Vt    = xb;                        // alias: xb dead after QKV GEMM
  unsigned short* P     = QKVb;                      // alias: QKVb dead after scores GEMM

  // 1) converts to bf16 (+ fused weight concat [Wq;Wk;Wv])
  cvt_kernel<<<dim3(MROWS * DMODEL / 4 / 256), 256, 0, stream>>>(x, (ushort4*)xb, MROWS * DMODEL / 4);
  cvt_kernel<<<dim3(1024), 256, 0, stream>>>(Wq, (ushort4*)Wqkvb, DMODEL * DMODEL / 4);
  cvt_kernel<<<dim3(1024), 256, 0, stream>>>(Wk, (ushort4*)(Wqkvb + 1048576), DMODEL * DMODEL / 4);
  cvt_kernel<<<dim3(1024), 256, 0, stream>>>(Wv, (ushort4*)(Wqkvb + 2097152), DMODEL * DMODEL / 4);
  hipMemcpyAsync(bqkv, bq, 4096, hipMemcpyDeviceToDevice, stream);
  hipMemcpyAsync(bqkv + 1024, bk, 4096, hipMemcpyDeviceToDevice, stream);
  hipMemcpyAsync(bqkv + 2048, bv, 4096, hipMemcpyDeviceToDevice, stream);

  // 2) fused QKV projection: [8192x3072] = x * Wqkv^T + bqkv (M=8192,N=3072,K=1024)
  gemm8<256, 0><<<dim3(12, 32, 1), 512, 0, stream>>>(
      xb, Wqkvb, QKVb, bqkv, 1024, 1024, 3072, 16, 1.f, 0, 0, 0);

  // 3) transpose V cols -> Vt [4][1024][2048]
  transpose_kernel<<<dim3(S_LEN / 32, DMODEL / 32, NBATCH), 256, 0, stream>>>(QKVb, Vt);

  // 4) scores: Sb = Q * K^T * 0.125 (per batch M=N=2048, K=1024; Q/K strided in QKVb)
  gemm8<256, 1><<<dim3(8, 8, 4), 512, 0, stream>>>(
      QKVb, QKVb + 1024, Sb, nullptr, 3072, 3072, 2048, 16, 0.125f,
      (long)S_LEN * 3072, (long)S_LEN * 3072, (long)S_LEN * S_LEN);

  // 5) row softmax -> bf16 P
  softmax_kernel<<<dim3(MROWS), 256, 0, stream>>>(Sb, P);

  // 6) out = P * Vt^T (per batch M=2048, N=1024, K=2048)
  gemm8<128, 2><<<dim3(4, 16, 4), 512, 0, stream>>>(
      P, Vt, out, nullptr, 2048, 2048, 1024, 32, 1.f,
      (long)S_LEN * S_LEN, (long)DMODEL * S_LEN, (long)S_LEN * DMODEL);
}

// Round 7
// 183.404 us; speedup vs baseline: 1.1466x; 1.0039x over previous
//
#include <hip/hip_runtime.h>
#include <stdint.h>

#define S_LEN 2048
#define DMODEL 1024
#define NBATCH 4
#define MROWS (NBATCH * S_LEN)  // 8192

typedef __bf16 bf16x8 __attribute__((ext_vector_type(8)));
typedef float f32x4 __attribute__((ext_vector_type(4)));

__device__ __forceinline__ unsigned short f2bf(float f) {
  unsigned int x = __builtin_bit_cast(unsigned int, f);
  x += 0x7FFFu + ((x >> 16) & 1u);
  return (unsigned short)(x >> 16);
}

template <int N>
__device__ __forceinline__ void waitvm() {
  static_assert(N <= 8, "vmcnt range");
  if constexpr (N < 0) {}
  else if constexpr (N == 0) asm volatile("s_waitcnt vmcnt(0)" ::: "memory");
  else if constexpr (N == 1) asm volatile("s_waitcnt vmcnt(1)" ::: "memory");
  else if constexpr (N == 2) asm volatile("s_waitcnt vmcnt(2)" ::: "memory");
  else if constexpr (N == 3) asm volatile("s_waitcnt vmcnt(3)" ::: "memory");
  else if constexpr (N == 4) asm volatile("s_waitcnt vmcnt(4)" ::: "memory");
  else if constexpr (N == 5) asm volatile("s_waitcnt vmcnt(5)" ::: "memory");
  else if constexpr (N == 6) asm volatile("s_waitcnt vmcnt(6)" ::: "memory");
  else if constexpr (N == 7) asm volatile("s_waitcnt vmcnt(7)" ::: "memory");
  else asm volatile("s_waitcnt vmcnt(8)" ::: "memory");
}
#define BARRIER() do { __builtin_amdgcn_s_barrier(); asm volatile("" ::: "memory"); } while (0)

// ---------------- convert f32 -> bf16 (vectorized) ----------------
__global__ void cvt_kernel(const float* __restrict__ src, ushort4* __restrict__ dst, int n4) {
  int i = blockIdx.x * blockDim.x + threadIdx.x;
  if (i < n4) {
    float4 v = reinterpret_cast<const float4*>(src)[i];
    ushort4 o;
    o.x = f2bf(v.x); o.y = f2bf(v.y); o.z = f2bf(v.z); o.w = f2bf(v.w);
    dst[i] = o;
  }
}

// ---------------- 6-phase balanced GEMM: C = A * B^T ----------------
// A: [M x K] bf16 row-major (lda); Bm: [N x K] bf16 row-major (ldb).
// 512 threads = 8 waves (2M x 4N). BN=256 fixed, BM in {128,256}. BK=64.
// kk-granular sub-quadrant walk:
//   P0:(0,0,k0) P1:(0,1,k0) P2:(0,1,k1) P3:(0,0,k1) P4:(1,0,k1)+(1,1,k1)
//   P5:(1,1,k0)+(1,0,k0)
// All 4 B-sets (bvv[nh][kk]) read ONCE per tile and held; A-half-kk sets
// read into rotating avA/avB. Reads/phase: 6,2,6,2,4,4. 6 barriers/tile.
// Stage slots (tile t stages t+1): P0:A0' P2:B0' P4:B1' P5:A1'.
// GUARD RULE (round-6 bug fix): reads at phase p execute between
// barrier(p-1) and barrier(p) => a half first READ at phase p must be
// vmcnt-guarded in phase p-1 (before that phase's barrier).
// First reads: A0k0/B0k0 @P0 (guarded by prev P5), B1k0 @P1 (guard @P0),
// B0k1 @P3 (resident), A1k1 @P4 (guard @P3), A1k0 @P5 (resident).
// Derived vmcnt (loads allowed to stay in flight):
//   BM256: P0 vm<4>, P3 vm<4>, P5 vm<4>; prologue vm<4>; drain P0 vm<2>, P3 vm<0>
//   BM128: P0 vm<2>, P3 vm<3>, P5 vm<3>; prologue vm<3>; drain P0 vm<1>, P3 vm<0>
// WAR (t+1 stages overwrite buf(t)): each region's last ds_read is drained
// by the lgkmcnt wait before that phase's MFMA (executed before the next
// barrier); earliest overwrite of the same region is >=2 barriers later.
// Quadrant (mh,nh) reads EXACTLY the staged contiguous halves across waves:
//   A row = mh*(BM/2) + wm*(BM/4) + m*16 + frow
//   B row = nh*128    + wn*32     + nn*16 + frow
// LDS swizzle: 16B-slot index ^= (row&7), via pre-swizzled GLOBAL source
// (linear LDS dest, rule #21) and identically on ds_read.
// EP: 0 = bf16 out + bias[col]; 1 = f32 out * scale; 2 = f32 out
template <int BM_, int EP>
__global__ __launch_bounds__(512, 2) void gemm8(
    const unsigned short* __restrict__ A, const unsigned short* __restrict__ Bm,
    void* __restrict__ Cp, const float* __restrict__ bias,
    int lda, int ldb, int ldc, int NT, float scale,
    long zsA, long zsB, long zsC) {
  constexpr int BN_ = 256;
  constexpr int BK = 64;                 // elements (128 bytes)
  constexpr int RA = BM_ / 128;          // stage loads per A-half per wave
  constexpr int HALF_A = (BM_ / 2) * 128;  // bytes
  constexpr int HALF_B = 128 * 128;
  constexpr int ATILE = BM_ * 128;
  constexpr int BTILE = BN_ * 128;
  constexpr int MREP = BM_ / 32;         // 8 or 4
  constexpr int MQ = MREP / 2;           // A frags per half (4 or 2)
  constexpr int VPRO = (BM_ == 256) ? 4 : 3;
  constexpr int V_P0 = (BM_ == 256) ? 4 : 2;
  constexpr int V_P3 = (BM_ == 256) ? 4 : 3;
  constexpr int V_P5 = (BM_ == 256) ? 4 : 3;
  constexpr int VD_P0 = (BM_ == 256) ? 2 : 1;

  __shared__ alignas(16) char lds[(ATILE + BTILE) * 2];

  const int tid = threadIdx.x;
  const int l = tid & 63;
  const int w = tid >> 6;   // 0..7
  const int wm = w >> 2;    // 0..1
  const int wn = w & 3;     // 0..3

  // bijective XCD-chunked swizzle (nwg % 8 == 0 for all our grids)
  const int gx = gridDim.x;
  const int nwg = gridDim.x * gridDim.y;
  int n = blockIdx.y * gx + blockIdx.x;
  int n2 = (n & 7) * (nwg >> 3) + (n >> 3);
  const int tileM = (n2 / gx) * BM_;
  const int tileN = (n2 % gx) * BN_;

  const int z = blockIdx.z;
  const unsigned short* Ab = A + (size_t)z * zsA;
  const unsigned short* Bb = Bm + (size_t)z * zsB;

  // staging: per-lane pre-swizzled global col; linear LDS dest (wave-uniform base)
  const int srow = l >> 3;                       // 0..7 within 8-row wave chunk
  const int scol = (((l & 7) ^ srow) * 16);      // swizzled byte col within 128B row

  auto stageA = [&](int buf, int t, int h) {
#pragma unroll
    for (int r = 0; r < RA; ++r) {
      int row = h * (BM_ / 2) + r * 64 + w * 8 + srow;
      const char* g = (const char*)(Ab + (size_t)(tileM + row) * lda + t * BK) + scol;
      char* d = lds + buf * (ATILE + BTILE) + h * HALF_A + r * 8192 + w * 1024;
      __builtin_amdgcn_global_load_lds(
          (const __attribute__((address_space(1))) void*)g,
          (__attribute__((address_space(3))) void*)d, 16, 0, 0);
    }
  };
  auto stageB = [&](int buf, int t, int h) {
#pragma unroll
    for (int r = 0; r < 2; ++r) {
      int row = h * 128 + r * 64 + w * 8 + srow;
      const char* g = (const char*)(Bb + (size_t)(tileN + row) * ldb + t * BK) + scol;
      char* d = lds + buf * (ATILE + BTILE) + ATILE + h * HALF_B + r * 8192 + w * 1024;
      __builtin_amdgcn_global_load_lds(
          (const __attribute__((address_space(1))) void*)g,
          (__attribute__((address_space(3))) void*)d, 16, 0, 0);
    }
  };

  f32x4 acc[MREP][4];
#pragma unroll
  for (int m = 0; m < MREP; ++m)
#pragma unroll
    for (int nn = 0; nn < 4; ++nn) acc[m][nn] = f32x4{0.f, 0.f, 0.f, 0.f};

  // fragment ds_read (same XOR swizzle as staging)
  const int frow = l & 15;
  auto rdA = [&](int buf, int mh, int m, int kk) -> bf16x8 {
    int row = mh * (BM_ / 2) + wm * (BM_ / 4) + m * 16 + frow;
    int col = (kk * 64 + ((l >> 4) * 16)) ^ ((row & 7) << 4);
    return *reinterpret_cast<const bf16x8*>(lds + buf * (ATILE + BTILE) + row * 128 + col);
  };
  auto rdB = [&](int buf, int nh, int nn, int kk) -> bf16x8 {
    int row = nh * 128 + wn * 32 + nn * 16 + frow;
    int col = (kk * 64 + ((l >> 4) * 16)) ^ ((row & 7) << 4);
    return *reinterpret_cast<const bf16x8*>(lds + buf * (ATILE + BTILE) + ATILE + row * 128 + col);
  };

  bf16x8 avA[MQ], avB[MQ];   // rotating A half-kk sets
  bf16x8 bvv[2][2][2];       // [nh][kk][nn] -- all four B sets held per tile

  auto rdAset = [&](int buf, int mh, int kk, bf16x8 (&dst)[MQ]) {
#pragma unroll
    for (int m = 0; m < MQ; ++m) dst[m] = rdA(buf, mh, m, kk);
  };
  auto rdBset = [&](int buf, int nh, int kk) {
#pragma unroll
    for (int nn = 0; nn < 2; ++nn) bvv[nh][kk][nn] = rdB(buf, nh, nn, kk);
  };
  auto mf8 = [&](bf16x8 (&av)[MQ], int mh, int nh, int kk) {
    __builtin_amdgcn_s_setprio(1);
#pragma unroll
    for (int m = 0; m < MQ; ++m)
#pragma unroll
      for (int nn = 0; nn < 2; ++nn)
        acc[mh * MQ + m][nh * 2 + nn] = __builtin_amdgcn_mfma_f32_16x16x32_bf16(
            av[m], bvv[nh][kk][nn], acc[mh * MQ + m][nh * 2 + nn], 0, 0, 0);
    __builtin_amdgcn_s_setprio(0);
  };

  // prologue: stage tile 0 (order A0,B0,B1,A1); guard A0,B0 resident
  stageA(0, 0, 0);
  stageB(0, 0, 0);
  stageB(0, 0, 1);
  stageA(0, 0, 1);
  waitvm<VPRO>();
  BARRIER();

  for (int t = 0; t < NT - 1; ++t) {
    const int buf = t & 1, nb = buf ^ 1;
    // P0: (0,0,k0); stage A0'; guard B1(t) for P1's reads
    rdAset(buf, 0, 0, avA); rdBset(buf, 0, 0);
    stageA(nb, t + 1, 0); waitvm<V_P0>(); BARRIER();
    mf8(avA, 0, 0, 0);
    // P1: (0,1,k0)
    rdBset(buf, 1, 0);
    BARRIER();
    mf8(avA, 0, 1, 0);
    // P2: (0,1,k1); stage B0'
    rdAset(buf, 0, 1, avB); rdBset(buf, 1, 1);
    stageB(nb, t + 1, 0); BARRIER();
    mf8(avB, 0, 1, 1);
    // P3: (0,0,k1); guard A1(t) for P4's reads
    rdBset(buf, 0, 1);
    waitvm<V_P3>(); BARRIER();
    mf8(avB, 0, 0, 1);
    // P4: (1,0,k1)+(1,1,k1); stage B1'
    rdAset(buf, 1, 1, avA);
    stageB(nb, t + 1, 1); BARRIER();
    mf8(avA, 1, 0, 1); mf8(avA, 1, 1, 1);
    // P5: (1,1,k0)+(1,0,k0); stage A1'; guard A0',B0' for t+1.P0
    rdAset(buf, 1, 0, avB);
    stageA(nb, t + 1, 1);
    waitvm<V_P5>(); BARRIER();
    mf8(avB, 1, 1, 0); mf8(avB, 1, 0, 0);
  }
  {  // peeled last tile: no staging; drain counted waits (same guard rule)
    const int buf = (NT - 1) & 1;
    // P0: guard B1 for P1
    rdAset(buf, 0, 0, avA); rdBset(buf, 0, 0); waitvm<VD_P0>(); BARRIER();
    mf8(avA, 0, 0, 0);
    rdBset(buf, 1, 0); BARRIER();
    mf8(avA, 0, 1, 0);
    rdAset(buf, 0, 1, avB); rdBset(buf, 1, 1); BARRIER();
    mf8(avB, 0, 1, 1);
    // P3: guard A1 for P4
    rdBset(buf, 0, 1); waitvm<0>(); BARRIER();
    mf8(avB, 0, 0, 1);
    rdAset(buf, 1, 1, avA); BARRIER();
    mf8(avA, 1, 0, 1); mf8(avA, 1, 1, 1);
    rdAset(buf, 1, 0, avB); BARRIER();
    mf8(avB, 1, 1, 0); mf8(avB, 1, 0, 0);
  }

  // epilogue: C/D layout (m89): col = lane&15, row = (lane>>4)*4 + j
  const int lr = (l >> 4) * 4;
  const int lc = l & 15;
#pragma unroll
  for (int mh = 0; mh < 2; ++mh) {
#pragma unroll
    for (int m = 0; m < MQ; ++m) {
#pragma unroll
      for (int nh = 0; nh < 2; ++nh) {
#pragma unroll
        for (int nn = 0; nn < 2; ++nn) {
          int gr = tileM + mh * (BM_ / 2) + wm * (BM_ / 4) + m * 16 + lr;
          int gc = tileN + nh * 128 + wn * 32 + nn * 16 + lc;
          f32x4 v = acc[mh * MQ + m][nh * 2 + nn];
          if constexpr (EP == 0) {
            float bb = bias[gc];
            unsigned short* C = (unsigned short*)Cp + (size_t)z * zsC;
#pragma unroll
            for (int j = 0; j < 4; ++j) C[(size_t)(gr + j) * ldc + gc] = f2bf(v[j] + bb);
          } else {
            float* C = (float*)Cp + (size_t)z * zsC;
#pragma unroll
            for (int j = 0; j < 4; ++j)
              C[(size_t)(gr + j) * ldc + gc] = (EP == 1) ? v[j] * scale : v[j];
          }
        }
      }
    }
  }
}

// ---------------- transpose bf16 V cols of QKV [S x 3072] -> Vt [D x S] per batch ----------------
__global__ void transpose_kernel(const unsigned short* __restrict__ src,
                                 unsigned short* __restrict__ dst) {
  __shared__ unsigned short tile[32][33];
  int b = blockIdx.z;
  int s0 = blockIdx.x * 32;
  int d0 = blockIdx.y * 32;
  int t = threadIdx.x;
  int r = t >> 3;
  int c4 = (t & 7) * 4;
  const unsigned short* sp = src + ((size_t)b * S_LEN + s0 + r) * 3072 + 2048 + d0 + c4;
  ushort4 v = *reinterpret_cast<const ushort4*>(sp);
  tile[r][c4 + 0] = v.x; tile[r][c4 + 1] = v.y; tile[r][c4 + 2] = v.z; tile[r][c4 + 3] = v.w;
  __syncthreads();
  unsigned short* dp = dst + ((size_t)b * DMODEL + d0 + r) * S_LEN + s0 + c4;
  ushort4 o;
  o.x = tile[c4 + 0][r]; o.y = tile[c4 + 1][r]; o.z = tile[c4 + 2][r]; o.w = tile[c4 + 3][r];
  *reinterpret_cast<ushort4*>(dp) = o;
}

// ---------------- row softmax: fp32 [8192 x 2048] -> bf16 P ----------------
__global__ __launch_bounds__(256) void softmax_kernel(const float* __restrict__ Sb,
                                                      unsigned short* __restrict__ P) {
  const size_t row = blockIdx.x;
  const float* sp = Sb + row * S_LEN;
  const int t = threadIdx.x;
  const int wid = t >> 6, lane = t & 63;
  float4 v0 = reinterpret_cast<const float4*>(sp)[t * 2];
  float4 v1 = reinterpret_cast<const float4*>(sp)[t * 2 + 1];
  float s[8] = {v0.x, v0.y, v0.z, v0.w, v1.x, v1.y, v1.z, v1.w};
  float mx = s[0];
#pragma unroll
  for (int i = 1; i < 8; ++i) mx = fmaxf(mx, s[i]);
#pragma unroll
  for (int o = 32; o > 0; o >>= 1) mx = fmaxf(mx, __shfl_xor(mx, o));
  __shared__ float redm[4];
  __shared__ float reds[4];
  if (lane == 0) redm[wid] = mx;
  __syncthreads();
  mx = fmaxf(fmaxf(redm[0], redm[1]), fmaxf(redm[2], redm[3]));
  float e[8];
  float sum = 0.f;
#pragma unroll
  for (int i = 0; i < 8; ++i) { e[i] = __expf(s[i] - mx); sum += e[i]; }
#pragma unroll
  for (int o = 32; o > 0; o >>= 1) sum += __shfl_xor(sum, o);
  if (lane == 0) reds[wid] = sum;
  __syncthreads();
  sum = reds[0] + reds[1] + reds[2] + reds[3];
  float inv = 1.0f / sum;
  ushort4 o0, o1;
  o0.x = f2bf(e[0] * inv); o0.y = f2bf(e[1] * inv); o0.z = f2bf(e[2] * inv); o0.w = f2bf(e[3] * inv);
  o1.x = f2bf(e[4] * inv); o1.y = f2bf(e[5] * inv); o1.z = f2bf(e[6] * inv); o1.w = f2bf(e[7] * inv);
  ushort4* dp = reinterpret_cast<ushort4*>(P + row * S_LEN);
  dp[t * 2] = o0;
  dp[t * 2 + 1] = o1;
}

extern "C" void kernel_launch(void* const* d_in, const int* in_sizes, int n_in,
                              void* d_out, int out_size, void* d_ws, size_t ws_size,
                              hipStream_t stream) {
  (void)in_sizes; (void)n_in; (void)out_size;
  const float* x = (const float*)d_in[0];
  const float* Wq = (const float*)d_in[1];
  const float* bq = (const float*)d_in[2];
  const float* Wk = (const float*)d_in[3];
  const float* bk = (const float*)d_in[4];
  const float* Wv = (const float*)d_in[5];
  const float* bv = (const float*)d_in[6];
  float* out = (float*)d_out;

  // workspace layout (bytes), total 140,509,184:
  //   xb    bf16 [8192][1024]  @ 0        (16 MB)  -- reused as Vt after QKV GEMM
  //   Wqkvb bf16 [3072][1024]  @ 16 MB    (6 MB)
  //   QKVb  bf16 [8192][3072]  @ 22 MB    (48 MB)  -- reused as P after scores GEMM
  //   Sb    f32  [4][2048][2048] @ 70 MB  (64 MB)  -- bqkv f32[3072] aliases its head
  if (ws_size < 140509184ull) return;
  char* ws = (char*)d_ws;
  unsigned short* xb    = (unsigned short*)(ws);
  unsigned short* Wqkvb = (unsigned short*)(ws + 16777216);
  unsigned short* QKVb  = (unsigned short*)(ws + 23068672);
  float*          Sb    = (float*)(ws + 73400320);
  float*          bqkv  = (float*)(ws + 73400320);  // alias: dead before Sb written
  unsigned short* Vt    = xb;                        // alias: xb dead after QKV GEMM
  unsigned short* P     = QKVb;                      // alias: QKVb dead after scores GEMM

  // 1) converts to bf16 (+ fused weight concat [Wq;Wk;Wv])
  cvt_kernel<<<dim3(MROWS * DMODEL / 4 / 256), 256, 0, stream>>>(x, (ushort4*)xb, MROWS * DMODEL / 4);
  cvt_kernel<<<dim3(1024), 256, 0, stream>>>(Wq, (ushort4*)Wqkvb, DMODEL * DMODEL / 4);
  cvt_kernel<<<dim3(1024), 256, 0, stream>>>(Wk, (ushort4*)(Wqkvb + 1048576), DMODEL * DMODEL / 4);
  cvt_kernel<<<dim3(1024), 256, 0, stream>>>(Wv, (ushort4*)(Wqkvb + 2097152), DMODEL * DMODEL / 4);
  hipMemcpyAsync(bqkv, bq, 4096, hipMemcpyDeviceToDevice, stream);
  hipMemcpyAsync(bqkv + 1024, bk, 4096, hipMemcpyDeviceToDevice, stream);
  hipMemcpyAsync(bqkv + 2048, bv, 4096, hipMemcpyDeviceToDevice, stream);

  // 2) fused QKV projection: [8192x3072] = x * Wqkv^T + bqkv (M=8192,N=3072,K=1024)
  gemm8<256, 0><<<dim3(12, 32, 1), 512, 0, stream>>>(
      xb, Wqkvb, QKVb, bqkv, 1024, 1024, 3072, 16, 1.f, 0, 0, 0);

  // 3) transpose V cols -> Vt [4][1024][2048]
  transpose_kernel<<<dim3(S_LEN / 32, DMODEL / 32, NBATCH), 256, 0, stream>>>(QKVb, Vt);

  // 4) scores: Sb = Q * K^T * 0.125 (per batch M=N=2048, K=1024; Q/K strided in QKVb)
  gemm8<256, 1><<<dim3(8, 8, 4), 512, 0, stream>>>(
      QKVb, QKVb + 1024, Sb, nullptr, 3072, 3072, 2048, 16, 0.125f,
      (long)S_LEN * 3072, (long)S_LEN * 3072, (long)S_LEN * S_LEN);

  // 5) row softmax -> bf16 P
  softmax_kernel<<<dim3(MROWS), 256, 0, stream>>>(Sb, P);

  // 6) out = P * Vt^T (per batch M=2048, N=1024, K=2048)
  gemm8<128, 2><<<dim3(4, 16, 4), 512, 0, stream>>>(
      P, Vt, out, nullptr, 2048, 2048, 1024, 32, 1.f,
      (long)S_LEN * S_LEN, (long)DMODEL * S_LEN, (long)S_LEN * DMODEL);
}

// Round 8
// 176.473 us; speedup vs baseline: 1.1917x; 1.0393x over previous
//
#include <hip/hip_runtime.h>
#include <stdint.h>

#define S_LEN 2048
#define DMODEL 1024
#define NBATCH 4
#define MROWS (NBATCH * S_LEN)  // 8192

typedef __bf16 bf16x8 __attribute__((ext_vector_type(8)));
typedef float f32x4 __attribute__((ext_vector_type(4)));

__device__ __forceinline__ unsigned short f2bf(float f) {
  unsigned int x = __builtin_bit_cast(unsigned int, f);
  x += 0x7FFFu + ((x >> 16) & 1u);
  return (unsigned short)(x >> 16);
}

template <int N>
__device__ __forceinline__ void waitvm() {
  static_assert(N <= 8, "vmcnt range");
  if constexpr (N < 0) {}
  else if constexpr (N == 0) asm volatile("s_waitcnt vmcnt(0)" ::: "memory");
  else if constexpr (N == 1) asm volatile("s_waitcnt vmcnt(1)" ::: "memory");
  else if constexpr (N == 2) asm volatile("s_waitcnt vmcnt(2)" ::: "memory");
  else if constexpr (N == 3) asm volatile("s_waitcnt vmcnt(3)" ::: "memory");
  else if constexpr (N == 4) asm volatile("s_waitcnt vmcnt(4)" ::: "memory");
  else if constexpr (N == 5) asm volatile("s_waitcnt vmcnt(5)" ::: "memory");
  else if constexpr (N == 6) asm volatile("s_waitcnt vmcnt(6)" ::: "memory");
  else if constexpr (N == 7) asm volatile("s_waitcnt vmcnt(7)" ::: "memory");
  else asm volatile("s_waitcnt vmcnt(8)" ::: "memory");
}
#define BARRIER() do { __builtin_amdgcn_s_barrier(); asm volatile("" ::: "memory"); } while (0)

// ---------------- convert f32 -> bf16 (vectorized) ----------------
__global__ void cvt_kernel(const float* __restrict__ src, ushort4* __restrict__ dst, int n4) {
  int i = blockIdx.x * blockDim.x + threadIdx.x;
  if (i < n4) {
    float4 v = reinterpret_cast<const float4*>(src)[i];
    ushort4 o;
    o.x = f2bf(v.x); o.y = f2bf(v.y); o.z = f2bf(v.z); o.w = f2bf(v.w);
    dst[i] = o;
  }
}

// ---------------- 6-phase balanced GEMM: C = A * B^T (r7-proven) ----------------
// A: [M x K] bf16 row-major (lda); Bm: [N x K] bf16 row-major (ldb).
// 512 threads = 8 waves (2M x 4N). BN=256 fixed, BM in {128,256}. BK=64.
// kk-granular sub-quadrant walk:
//   P0:(0,0,k0) P1:(0,1,k0) P2:(0,1,k1) P3:(0,0,k1) P4:(1,0,k1)+(1,1,k1)
//   P5:(1,1,k0)+(1,0,k0)
// All 4 B-sets (bvv[nh][kk]) read ONCE per tile and held; A-half-kk sets
// read into rotating avA/avB. Reads/phase: 6,2,6,2,4,4. 6 barriers/tile.
// Stage slots (tile t stages t+1): P0:A0' P2:B0' P4:B1' P5:A1'.
// GUARD RULE: reads at phase p execute between barrier(p-1) and barrier(p)
// => a half first READ at phase p must be vmcnt-guarded in phase p-1.
// First reads: A0k0/B0k0 @P0 (guarded by prev P5), B1k0 @P1 (guard @P0),
// B0k1 @P3 (resident), A1k1 @P4 (guard @P3), A1k0 @P5 (resident).
// Derived vmcnt:
//   BM256: P0 vm<4>, P3 vm<4>, P5 vm<4>; prologue vm<4>; drain P0 vm<2>, P3 vm<0>
//   BM128: P0 vm<2>, P3 vm<3>, P5 vm<3>; prologue vm<3>; drain P0 vm<1>, P3 vm<0>
// Quadrant (mh,nh) reads EXACTLY the staged contiguous halves across waves:
//   A row = mh*(BM/2) + wm*(BM/4) + m*16 + frow
//   B row = nh*128    + wn*32     + nn*16 + frow
// LDS swizzle: 16B-slot index ^= (row&7), via pre-swizzled GLOBAL source
// (linear LDS dest, rule #21) and identically on ds_read.
// EP: 0 = bf16 out + bias[col]; 1 = f32 out * scale; 2 = f32 out;
//     3 = bf16 out + bias[ROW]  (used for Vt = Wv * x^T + bv)
template <int BM_, int EP>
__global__ __launch_bounds__(512, 2) void gemm8(
    const unsigned short* __restrict__ A, const unsigned short* __restrict__ Bm,
    void* __restrict__ Cp, const float* __restrict__ bias,
    int lda, int ldb, int ldc, int NT, float scale,
    long zsA, long zsB, long zsC) {
  constexpr int BN_ = 256;
  constexpr int BK = 64;                 // elements (128 bytes)
  constexpr int RA = BM_ / 128;          // stage loads per A-half per wave
  constexpr int HALF_A = (BM_ / 2) * 128;  // bytes
  constexpr int HALF_B = 128 * 128;
  constexpr int ATILE = BM_ * 128;
  constexpr int BTILE = BN_ * 128;
  constexpr int MREP = BM_ / 32;         // 8 or 4
  constexpr int MQ = MREP / 2;           // A frags per half (4 or 2)
  constexpr int VPRO = (BM_ == 256) ? 4 : 3;
  constexpr int V_P0 = (BM_ == 256) ? 4 : 2;
  constexpr int V_P3 = (BM_ == 256) ? 4 : 3;
  constexpr int V_P5 = (BM_ == 256) ? 4 : 3;
  constexpr int VD_P0 = (BM_ == 256) ? 2 : 1;

  __shared__ alignas(16) char lds[(ATILE + BTILE) * 2];

  const int tid = threadIdx.x;
  const int l = tid & 63;
  const int w = tid >> 6;   // 0..7
  const int wm = w >> 2;    // 0..1
  const int wn = w & 3;     // 0..3

  // bijective XCD-chunked swizzle (nwg % 8 == 0 for all our grids)
  const int gx = gridDim.x;
  const int nwg = gridDim.x * gridDim.y;
  int n = blockIdx.y * gx + blockIdx.x;
  int n2 = (n & 7) * (nwg >> 3) + (n >> 3);
  const int tileM = (n2 / gx) * BM_;
  const int tileN = (n2 % gx) * BN_;

  const int z = blockIdx.z;
  const unsigned short* Ab = A + (size_t)z * zsA;
  const unsigned short* Bb = Bm + (size_t)z * zsB;

  // staging: per-lane pre-swizzled global col; linear LDS dest (wave-uniform base)
  const int srow = l >> 3;                       // 0..7 within 8-row wave chunk
  const int scol = (((l & 7) ^ srow) * 16);      // swizzled byte col within 128B row

  auto stageA = [&](int buf, int t, int h) {
#pragma unroll
    for (int r = 0; r < RA; ++r) {
      int row = h * (BM_ / 2) + r * 64 + w * 8 + srow;
      const char* g = (const char*)(Ab + (size_t)(tileM + row) * lda + t * BK) + scol;
      char* d = lds + buf * (ATILE + BTILE) + h * HALF_A + r * 8192 + w * 1024;
      __builtin_amdgcn_global_load_lds(
          (const __attribute__((address_space(1))) void*)g,
          (__attribute__((address_space(3))) void*)d, 16, 0, 0);
    }
  };
  auto stageB = [&](int buf, int t, int h) {
#pragma unroll
    for (int r = 0; r < 2; ++r) {
      int row = h * 128 + r * 64 + w * 8 + srow;
      const char* g = (const char*)(Bb + (size_t)(tileN + row) * ldb + t * BK) + scol;
      char* d = lds + buf * (ATILE + BTILE) + ATILE + h * HALF_B + r * 8192 + w * 1024;
      __builtin_amdgcn_global_load_lds(
          (const __attribute__((address_space(1))) void*)g,
          (__attribute__((address_space(3))) void*)d, 16, 0, 0);
    }
  };

  f32x4 acc[MREP][4];
#pragma unroll
  for (int m = 0; m < MREP; ++m)
#pragma unroll
    for (int nn = 0; nn < 4; ++nn) acc[m][nn] = f32x4{0.f, 0.f, 0.f, 0.f};

  // fragment ds_read (same XOR swizzle as staging)
  const int frow = l & 15;
  auto rdA = [&](int buf, int mh, int m, int kk) -> bf16x8 {
    int row = mh * (BM_ / 2) + wm * (BM_ / 4) + m * 16 + frow;
    int col = (kk * 64 + ((l >> 4) * 16)) ^ ((row & 7) << 4);
    return *reinterpret_cast<const bf16x8*>(lds + buf * (ATILE + BTILE) + row * 128 + col);
  };
  auto rdB = [&](int buf, int nh, int nn, int kk) -> bf16x8 {
    int row = nh * 128 + wn * 32 + nn * 16 + frow;
    int col = (kk * 64 + ((l >> 4) * 16)) ^ ((row & 7) << 4);
    return *reinterpret_cast<const bf16x8*>(lds + buf * (ATILE + BTILE) + ATILE + row * 128 + col);
  };

  bf16x8 avA[MQ], avB[MQ];   // rotating A half-kk sets
  bf16x8 bvv[2][2][2];       // [nh][kk][nn] -- all four B sets held per tile

  auto rdAset = [&](int buf, int mh, int kk, bf16x8 (&dst)[MQ]) {
#pragma unroll
    for (int m = 0; m < MQ; ++m) dst[m] = rdA(buf, mh, m, kk);
  };
  auto rdBset = [&](int buf, int nh, int kk) {
#pragma unroll
    for (int nn = 0; nn < 2; ++nn) bvv[nh][kk][nn] = rdB(buf, nh, nn, kk);
  };
  auto mf8 = [&](bf16x8 (&av)[MQ], int mh, int nh, int kk) {
    __builtin_amdgcn_s_setprio(1);
#pragma unroll
    for (int m = 0; m < MQ; ++m)
#pragma unroll
      for (int nn = 0; nn < 2; ++nn)
        acc[mh * MQ + m][nh * 2 + nn] = __builtin_amdgcn_mfma_f32_16x16x32_bf16(
            av[m], bvv[nh][kk][nn], acc[mh * MQ + m][nh * 2 + nn], 0, 0, 0);
    __builtin_amdgcn_s_setprio(0);
  };

  // prologue: stage tile 0 (order A0,B0,B1,A1); guard A0,B0 resident
  stageA(0, 0, 0);
  stageB(0, 0, 0);
  stageB(0, 0, 1);
  stageA(0, 0, 1);
  waitvm<VPRO>();
  BARRIER();

  for (int t = 0; t < NT - 1; ++t) {
    const int buf = t & 1, nb = buf ^ 1;
    // P0: (0,0,k0); stage A0'; guard B1(t) for P1's reads
    rdAset(buf, 0, 0, avA); rdBset(buf, 0, 0);
    stageA(nb, t + 1, 0); waitvm<V_P0>(); BARRIER();
    mf8(avA, 0, 0, 0);
    // P1: (0,1,k0)
    rdBset(buf, 1, 0);
    BARRIER();
    mf8(avA, 0, 1, 0);
    // P2: (0,1,k1); stage B0'
    rdAset(buf, 0, 1, avB); rdBset(buf, 1, 1);
    stageB(nb, t + 1, 0); BARRIER();
    mf8(avB, 0, 1, 1);
    // P3: (0,0,k1); guard A1(t) for P4's reads
    rdBset(buf, 0, 1);
    waitvm<V_P3>(); BARRIER();
    mf8(avB, 0, 0, 1);
    // P4: (1,0,k1)+(1,1,k1); stage B1'
    rdAset(buf, 1, 1, avA);
    stageB(nb, t + 1, 1); BARRIER();
    mf8(avA, 1, 0, 1); mf8(avA, 1, 1, 1);
    // P5: (1,1,k0)+(1,0,k0); stage A1'; guard A0',B0' for t+1.P0
    rdAset(buf, 1, 0, avB);
    stageA(nb, t + 1, 1);
    waitvm<V_P5>(); BARRIER();
    mf8(avB, 1, 1, 0); mf8(avB, 1, 0, 0);
  }
  {  // peeled last tile: no staging; drain counted waits (same guard rule)
    const int buf = (NT - 1) & 1;
    // P0: guard B1 for P1
    rdAset(buf, 0, 0, avA); rdBset(buf, 0, 0); waitvm<VD_P0>(); BARRIER();
    mf8(avA, 0, 0, 0);
    rdBset(buf, 1, 0); BARRIER();
    mf8(avA, 0, 1, 0);
    rdAset(buf, 0, 1, avB); rdBset(buf, 1, 1); BARRIER();
    mf8(avB, 0, 1, 1);
    // P3: guard A1 for P4
    rdBset(buf, 0, 1); waitvm<0>(); BARRIER();
    mf8(avB, 0, 0, 1);
    rdAset(buf, 1, 1, avA); BARRIER();
    mf8(avA, 1, 0, 1); mf8(avA, 1, 1, 1);
    rdAset(buf, 1, 0, avB); BARRIER();
    mf8(avB, 1, 1, 0); mf8(avB, 1, 0, 0);
  }

  // epilogue: C/D layout (m89): col = lane&15, row = (lane>>4)*4 + j
  const int lr = (l >> 4) * 4;
  const int lc = l & 15;
#pragma unroll
  for (int mh = 0; mh < 2; ++mh) {
#pragma unroll
    for (int m = 0; m < MQ; ++m) {
#pragma unroll
      for (int nh = 0; nh < 2; ++nh) {
#pragma unroll
        for (int nn = 0; nn < 2; ++nn) {
          int gr = tileM + mh * (BM_ / 2) + wm * (BM_ / 4) + m * 16 + lr;
          int gc = tileN + nh * 128 + wn * 32 + nn * 16 + lc;
          f32x4 v = acc[mh * MQ + m][nh * 2 + nn];
          if constexpr (EP == 0 || EP == 3) {
            unsigned short* C = (unsigned short*)Cp + (size_t)z * zsC;
#pragma unroll
            for (int j = 0; j < 4; ++j) {
              float bb = (EP == 0) ? bias[gc] : bias[gr + j];
              C[(size_t)(gr + j) * ldc + gc] = f2bf(v[j] + bb);
            }
          } else {
            float* C = (float*)Cp + (size_t)z * zsC;
#pragma unroll
            for (int j = 0; j < 4; ++j)
              C[(size_t)(gr + j) * ldc + gc] = (EP == 1) ? v[j] * scale : v[j];
          }
        }
      }
    }
  }
}

// ---------------- row softmax: fp32 [8192 x 2048] -> bf16 P ----------------
__global__ __launch_bounds__(256) void softmax_kernel(const float* __restrict__ Sb,
                                                      unsigned short* __restrict__ P) {
  const size_t row = blockIdx.x;
  const float* sp = Sb + row * S_LEN;
  const int t = threadIdx.x;
  const int wid = t >> 6, lane = t & 63;
  float4 v0 = reinterpret_cast<const float4*>(sp)[t * 2];
  float4 v1 = reinterpret_cast<const float4*>(sp)[t * 2 + 1];
  float s[8] = {v0.x, v0.y, v0.z, v0.w, v1.x, v1.y, v1.z, v1.w};
  float mx = s[0];
#pragma unroll
  for (int i = 1; i < 8; ++i) mx = fmaxf(mx, s[i]);
#pragma unroll
  for (int o = 32; o > 0; o >>= 1) mx = fmaxf(mx, __shfl_xor(mx, o));
  __shared__ float redm[4];
  __shared__ float reds[4];
  if (lane == 0) redm[wid] = mx;
  __syncthreads();
  mx = fmaxf(fmaxf(redm[0], redm[1]), fmaxf(redm[2], redm[3]));
  float e[8];
  float sum = 0.f;
#pragma unroll
  for (int i = 0; i < 8; ++i) { e[i] = __expf(s[i] - mx); sum += e[i]; }
#pragma unroll
  for (int o = 32; o > 0; o >>= 1) sum += __shfl_xor(sum, o);
  if (lane == 0) reds[wid] = sum;
  __syncthreads();
  sum = reds[0] + reds[1] + reds[2] + reds[3];
  float inv = 1.0f / sum;
  ushort4 o0, o1;
  o0.x = f2bf(e[0] * inv); o0.y = f2bf(e[1] * inv); o0.z = f2bf(e[2] * inv); o0.w = f2bf(e[3] * inv);
  o1.x = f2bf(e[4] * inv); o1.y = f2bf(e[5] * inv); o1.z = f2bf(e[6] * inv); o1.w = f2bf(e[7] * inv);
  ushort4* dp = reinterpret_cast<ushort4*>(P + row * S_LEN);
  dp[t * 2] = o0;
  dp[t * 2 + 1] = o1;
}

extern "C" void kernel_launch(void* const* d_in, const int* in_sizes, int n_in,
                              void* d_out, int out_size, void* d_ws, size_t ws_size,
                              hipStream_t stream) {
  (void)in_sizes; (void)n_in; (void)out_size;
  const float* x = (const float*)d_in[0];
  const float* Wq = (const float*)d_in[1];
  const float* bq = (const float*)d_in[2];
  const float* Wk = (const float*)d_in[3];
  const float* bk = (const float*)d_in[4];
  const float* Wv = (const float*)d_in[5];
  const float* bv = (const float*)d_in[6];
  float* out = (float*)d_out;

  // workspace layout (bytes), total ~135 MB:
  //   xb   bf16 [8192][1024]    @ 0       (16 MB)  -- alive until Vt-GEMM done
  //   Wqkb bf16 [2048][1024]    @ 16 MB   (4 MB)   -- [Wq;Wk]
  //   Wvb  bf16 [1024][1024]    @ 20 MB   (2 MB)
  //   bqk  f32  [2048]          @ 22 MB   (8 KB)
  //   QKb  bf16 [8192][2048]    @ 23 MB   (32 MB)  -- Q cols 0..1023, K cols 1024..2047
  //                                                 -- reused as P after scores GEMM
  //   Sb   f32  [4][2048][2048] @ 55 MB   (64 MB)
  //   Vt   bf16 [4][1024][2048] @ 119 MB  (16 MB)
  if (ws_size < 141557760ull) return;
  char* ws = (char*)d_ws;
  unsigned short* xb   = (unsigned short*)(ws);
  unsigned short* Wqkb = (unsigned short*)(ws + 16777216);
  unsigned short* Wvb  = (unsigned short*)(ws + 20971520);
  float*          bqk  = (float*)(ws + 23068672);
  unsigned short* QKb  = (unsigned short*)(ws + 24117248);
  float*          Sb   = (float*)(ws + 57671680);
  unsigned short* Vt   = (unsigned short*)(ws + 124780544);
  unsigned short* P    = QKb;  // alias: QKb dead after scores GEMM

  // 1) converts to bf16 (+ fused weight concat [Wq;Wk])
  cvt_kernel<<<dim3(MROWS * DMODEL / 4 / 256), 256, 0, stream>>>(x, (ushort4*)xb, MROWS * DMODEL / 4);
  cvt_kernel<<<dim3(1024), 256, 0, stream>>>(Wq, (ushort4*)Wqkb, DMODEL * DMODEL / 4);
  cvt_kernel<<<dim3(1024), 256, 0, stream>>>(Wk, (ushort4*)(Wqkb + 1048576), DMODEL * DMODEL / 4);
  cvt_kernel<<<dim3(1024), 256, 0, stream>>>(Wv, (ushort4*)Wvb, DMODEL * DMODEL / 4);
  hipMemcpyAsync(bqk, bq, 4096, hipMemcpyDeviceToDevice, stream);
  hipMemcpyAsync(bqk + 1024, bk, 4096, hipMemcpyDeviceToDevice, stream);

  // 2) QK projection: [8192x2048] = x * [Wq;Wk]^T + bqk  (grid 256 = 1 round)
  gemm8<256, 0><<<dim3(8, 32, 1), 512, 0, stream>>>(
      xb, Wqkb, QKb, bqk, 1024, 1024, 2048, 16, 1.f, 0, 0, 0);

  // 3) Vt = Wv * x^T + bv (per batch): C[z][d][s] = Wv[d].x[z][s] + bv[d]
  //    M=1024, N=2048, K=1024; BM=128 -> grid (8,8,4) = 256 half-size blocks = 1 round
  gemm8<128, 3><<<dim3(8, 8, 4), 512, 0, stream>>>(
      Wvb, xb, Vt, bv, 1024, 1024, 2048, 16, 1.f,
      0, (long)S_LEN * DMODEL, (long)DMODEL * S_LEN);

  // 4) scores: Sb = Q * K^T * 0.125 (per batch M=N=2048, K=1024)
  gemm8<256, 1><<<dim3(8, 8, 4), 512, 0, stream>>>(
      QKb, QKb + 1024, Sb, nullptr, 2048, 2048, 2048, 16, 0.125f,
      (long)S_LEN * 2048, (long)S_LEN * 2048, (long)S_LEN * S_LEN);

  // 5) row softmax -> bf16 P (aliases QKb)
  softmax_kernel<<<dim3(MROWS), 256, 0, stream>>>(Sb, P);

  // 6) out = P * Vt^T (per batch M=2048, N=1024, K=2048; grid 256 = 1 round)
  gemm8<128, 2><<<dim3(4, 16, 4), 512, 0, stream>>>(
      P, Vt, out, nullptr, 2048, 2048, 1024, 32, 1.f,
      (long)S_LEN * S_LEN, (long)DMODEL * S_LEN, (long)S_LEN * DMODEL);
}